// Round 10
// baseline (253.007 us; speedup 1.0000x reference)
//
#include <hip/hip_runtime.h>

// Fused attention with masked-key compaction, 6 dispatches. R18 = R17 +
// R14's Q-GEMM elimination done right. Softmax is shift-invariant per row:
//   QK^T = x(Wq^T Wk)xc^T + 1·d^T + (per-row constants that cancel)
// with M = Wq^T·Wk (1024^2), d_k = xc_k·(Wk^T bq). So S = xh·Kc'^T/32 +
// d[col], Kc' = xc·M^T -- the 512-tile Q projection vanishes (-29us round
// time). R14 proved the numerics (passed, same absmax); it lost on impl:
// atomic M-partials + zeroing + mconv + pre-ILP prep. R18: M = WqT·WkT^T as
// 64 PLAIN gemm_body tiles (f16 out, no atomics) inside the BW-bound gather
// dispatch (overlaps); transpose/w fold into prep.
// Round model (calibrated R17): ~34.4MF/tile @ ~600TF aggregate -> 57us per
// 1024-tile round. R17 rounds: qk 784t=45 + sv 822t=47 + pv 512t=30.
// R18 rounds: kvt 544t=31 + s 550t=33 + pv 512t=30.
// R8 lesson: launch_bounds 2nd arg MUST be 4 on the 128-body (5 spills acc).
// R9/R10: deep pipelines regress here. R12: no addressing in K-loop.
// R13/R16: slots = 4/CU x 256 = 1024; tile counts > 1024 cost a full round.
//  L1 prep:  cast x,W->f16 (1408, ILP8) + mask scan (4) + transpose WqT/WkT
//            (512) + w = Wk^T bq (32)
//  L2 gm:    M tiles (64) + gather xc & dvec=(xc.w)/32 (2048)
//  L3 kvt:   Kc' = xc M^T (8n x MTp) + Vt = Wv xc^T + bv (8m x MTp), G=1024
//  L4 s:     S = (xh Kc'^T)/32 + dvec[col], Kc'-panel-grouped, G=1024
//  L5 softmax: wave-per-row
//  L6 pv:    O = P @ Vt^T (K=npad), Sbuf-panel-grouped, G=512
// GEMM core: BK=64, global_load_lds w=16, XOR-swizzled LDS (0 conflicts, R2).

typedef _Float16 f16;
typedef _Float16 f16x4 __attribute__((ext_vector_type(4)));
typedef _Float16 f16x8 __attribute__((ext_vector_type(8)));
typedef float f32x4 __attribute__((ext_vector_type(4)));

#define LB256 __launch_bounds__(256)

__device__ __forceinline__ void gld16(const void* gp, void* lp) {
  __builtin_amdgcn_global_load_lds(
      (__attribute__((address_space(1))) void*)(gp),
      (__attribute__((address_space(3))) void*)(lp),
      16, 0, 0);
}

// ---------------------------------------------------------------- 128x128 GEMM body
template <typename OutT>
__device__ __forceinline__ void gemm_body(
    f16* As, f16* Bs,
    const f16* __restrict__ A, int lda, const f16* __restrict__ B, int ldb,
    OutT* __restrict__ C, int ldc,
    const float* __restrict__ bias1, const float* __restrict__ bias2, int nb1,
    int bias_row, float scale, int K, int m0, int n0) {
  const int tid = threadIdx.x;
  const int w = tid >> 6, l = tid & 63;
  const int wm = (w >> 1) * 64, wn = (w & 1) * 64;
  const int quad = l >> 4, lo = l & 15;
  const int rl = l >> 3;
  const int scol = ((l & 7) ^ rl) * 8;
  const int swz = (quad ^ (lo & 3)) * 8;
  const int ks0 = ((lo >> 2) & 1) * 32;

  f32x4 acc[4][4] = {};
  for (int kk = 0; kk < K; kk += 64) {
#pragma unroll
    for (int r = 0; r < 4; ++r) {
      const int c8 = r * 4 + w;
      const int row = c8 * 8 + rl;
      gld16(A + (long)(m0 + row) * lda + kk + scol, &As[c8 * 512]);
      gld16(B + (long)(n0 + row) * ldb + kk + scol, &Bs[c8 * 512]);
    }
    __syncthreads();
#pragma unroll
    for (int ks = 0; ks < 2; ++ks) {
      const int kso = ks ? (32 - ks0) : ks0;
      f16x8 af[4], bf[4];
#pragma unroll
      for (int i = 0; i < 4; ++i)
        af[i] = *(const f16x8*)&As[(wm + i * 16 + lo) * 64 + swz + kso];
#pragma unroll
      for (int j = 0; j < 4; ++j)
        bf[j] = *(const f16x8*)&Bs[(wn + j * 16 + lo) * 64 + swz + kso];
#pragma unroll
      for (int i = 0; i < 4; ++i)
#pragma unroll
        for (int j = 0; j < 4; ++j)
          acc[i][j] = __builtin_amdgcn_mfma_f32_16x16x32_f16(af[i], bf[j],
                                                             acc[i][j], 0, 0, 0);
    }
    __syncthreads();
  }
#pragma unroll
  for (int i = 0; i < 4; ++i) {
    const int rowb = m0 + wm + i * 16 + quad * 4;
#pragma unroll
    for (int j = 0; j < 4; ++j) {
      const int col = n0 + wn + j * 16 + lo;
      float bc = 0.f;
      if (bias1 && !bias_row) bc = (col < nb1) ? bias1[col] : bias2[col - nb1];
#pragma unroll
      for (int r = 0; r < 4; ++r) {
        float bv = bias_row ? bias1[rowb + r] : bc;
        C[(long)(rowb + r) * ldc + col] = (OutT)(acc[i][j][r] * scale + bv);
      }
    }
  }
}

// ---------------------------------------------------------------- L1 prep
// [0,1408): ILP8 cast (1408*256*8 = 2883584 float4s exact).
// [1408,1412): per-batch mask scan. [1412,1924): transpose Wq,Wk -> f16
// WqT/WkT (64x64 tiles). [1924,1956): w = Wk^T bq (f32).
__global__ LB256 void prep(const float* __restrict__ x, const float* __restrict__ wq,
                           const float* __restrict__ wk, const float* __restrict__ wv,
                           const void* __restrict__ maskp, const float* __restrict__ bq,
                           f16* __restrict__ xh, f16* __restrict__ wh,
                           f16* __restrict__ wqt, f16* __restrict__ wkt,
                           float* __restrict__ wbuf, int* __restrict__ sel,
                           int* __restrict__ counts, int* __restrict__ npad) {
  const int blk = blockIdx.x;
  const int t = threadIdx.x;
  if (blk < 1408) {
    const long u0 = (long)blk * 256 + t;
    const float* srcp[8];
    f16* dstp[8];
#pragma unroll
    for (int j = 0; j < 8; ++j) {
      const long i = (u0 + (long)j * 360448) * 4;
      if (i < 8388608L) {
        srcp[j] = x + i;
        dstp[j] = xh + i;
      } else {
        const long jj = i - 8388608L;
        const int which = (int)(jj >> 20);
        const float* ws = which == 0 ? wq : (which == 1 ? wk : wv);
        srcp[j] = ws + (jj & 1048575L);
        dstp[j] = wh + jj;
      }
    }
    float4 v0 = *(const float4*)srcp[0];
    float4 v1 = *(const float4*)srcp[1];
    float4 v2 = *(const float4*)srcp[2];
    float4 v3 = *(const float4*)srcp[3];
    float4 v4 = *(const float4*)srcp[4];
    float4 v5 = *(const float4*)srcp[5];
    float4 v6 = *(const float4*)srcp[6];
    float4 v7 = *(const float4*)srcp[7];
#define CVT_ST(J, V)                                                   \
    do {                                                               \
      f16x4 o;                                                         \
      o[0] = (f16)V.x; o[1] = (f16)V.y; o[2] = (f16)V.z; o[3] = (f16)V.w; \
      *(f16x4*)dstp[J] = o;                                            \
    } while (0)
    CVT_ST(0, v0); CVT_ST(1, v1); CVT_ST(2, v2); CVT_ST(3, v3);
    CVT_ST(4, v4); CVT_ST(5, v5); CVT_ST(6, v6); CVT_ST(7, v7);
#undef CVT_ST
  } else if (blk < 1412) {
    const int b = blk - 1408;
    __shared__ int bad;
    __shared__ int s[256];
    if (t == 0) bad = 0;
    __syncthreads();
    const int* mi = (const int*)maskp;
    int loc = 0;
    for (int i = t; i < 2048; i += 256)
      if ((unsigned)mi[i] > 1u) loc = 1;  // byte-packed bools look like big ints
    if (loc) atomicOr(&bad, 1);
    __syncthreads();
    const bool bytemode = bad != 0;
    int m[8];
    if (bytemode) {
      const unsigned char* p = (const unsigned char*)maskp + b * 2048 + t * 8;
#pragma unroll
      for (int e = 0; e < 8; ++e) m[e] = p[e] != 0;
    } else {
      const int* p = mi + b * 2048 + t * 8;
#pragma unroll
      for (int e = 0; e < 8; ++e) m[e] = p[e] != 0;
    }
    int local = 0;
#pragma unroll
    for (int e = 0; e < 8; ++e) local += m[e];
    s[t] = local;
    __syncthreads();
    for (int off = 1; off < 256; off <<= 1) {
      int v = (t >= off) ? s[t - off] : 0;
      __syncthreads();
      s[t] += v;
      __syncthreads();
    }
    int offp = s[t] - local;
#pragma unroll
    for (int e = 0; e < 8; ++e)
      if (m[e]) sel[b * 2048 + offp++] = t * 8 + e;
    if (t == 0) {
      counts[b] = s[255];
      npad[b] = ((s[255] + 127) >> 7) << 7;
    }
  } else if (blk < 1924) {
    // transpose: dst[d][e] = src[e][d], 64x64 tiles (proven R14)
    const int u = blk - 1412;
    const float* src = (u >> 8) ? wk : wq;
    f16* dst = (u >> 8) ? wkt : wqt;
    const int tile = u & 255, tr = tile >> 4, tc = tile & 15;
    __shared__ f16 lt[64][68];
    const int r = t >> 2, cg = t & 3;
#pragma unroll
    for (int uu = 0; uu < 4; ++uu) {
      float4 v = *(const float4*)&src[(long)(tr * 64 + r) * 1024 + tc * 64 +
                                      cg * 16 + uu * 4];
      lt[r][cg * 16 + uu * 4 + 0] = (f16)v.x;
      lt[r][cg * 16 + uu * 4 + 1] = (f16)v.y;
      lt[r][cg * 16 + uu * 4 + 2] = (f16)v.z;
      lt[r][cg * 16 + uu * 4 + 3] = (f16)v.w;
    }
    __syncthreads();
    const int c = t >> 2, rg = t & 3;
    f16x8 o0, o1;
#pragma unroll
    for (int e = 0; e < 8; ++e) {
      o0[e] = lt[rg * 16 + e][c];
      o1[e] = lt[rg * 16 + 8 + e][c];
    }
    f16* drow = dst + (long)(tc * 64 + c) * 1024 + tr * 64 + rg * 16;
    *(f16x8*)drow = o0;
    *(f16x8*)(drow + 8) = o1;
  } else {
    // w[i] = sum_e Wk[e][i] * bq[e]  (proven R14)
    const int i0 = (blk - 1924) * 32;
    const int il = t & 31, part = t >> 5;
    float s = 0.f;
    for (int e = part; e < 1024; e += 8) s += wk[(long)e * 1024 + i0 + il] * bq[e];
    __shared__ float red[256];
    red[t] = s;
    __syncthreads();
    if (t < 32) {
      float a = 0.f;
#pragma unroll
      for (int pp = 0; pp < 8; ++pp) a += red[pp * 32 + t];
      wbuf[i0 + t] = a;
    }
  }
}

// ---------------------------------------------------------------- L2 gm
// [0,64): M = WqT·WkT^T, 64 plain 128^2 tiles, f16 out, no atomics.
// [64,2112): gather xc rows via sel + dvec = (xc.w)/32 (proven R14).
__global__ LB256 void gm(const f16* __restrict__ xh, const int* __restrict__ sel,
                         const int* __restrict__ counts, const int* __restrict__ npad,
                         f16* __restrict__ xc, const f16* __restrict__ wqt,
                         const f16* __restrict__ wkt, f16* __restrict__ Mh,
                         const float* __restrict__ wbuf, float* __restrict__ dvec) {
  __shared__ __align__(16) f16 As[128 * 64];
  __shared__ __align__(16) f16 Bs[128 * 64];
  const int t = threadIdx.x;
  if (blockIdx.x < 64) {
    const int m = blockIdx.x & 7, n = blockIdx.x >> 3;
    gemm_body<f16>(As, Bs, wqt, 1024, wkt, 1024, Mh, 1024, nullptr, nullptr, 0,
                   0, 1.0f, 1024, m * 128, n * 128);
    return;
  }
  const int g = blockIdx.x - 64;
  const int b = g >> 9, gx = g & 511;
  const int np = npad[b], cnt = counts[b];
  float* red = (float*)As;
#pragma unroll
  for (int i = 0; i < 4; ++i) {
    const int sp = gx * 4 + i;
    if (sp >= np) continue;  // block-uniform
    f16* dst = xc + ((long)b * 2048 + sp) * 1024;
    float dot = 0.f;
    if (sp >= cnt) {
      *(f16x4*)(dst + t * 4) = (f16x4){0, 0, 0, 0};
    } else {
      const f16* src = xh + ((long)b * 2048 + sel[b * 2048 + sp]) * 1024;
      f16x4 v = *(const f16x4*)(src + t * 4);
      *(f16x4*)(dst + t * 4) = v;
      dot = (float)v[0] * wbuf[t * 4] + (float)v[1] * wbuf[t * 4 + 1] +
            (float)v[2] * wbuf[t * 4 + 2] + (float)v[3] * wbuf[t * 4 + 3];
    }
#pragma unroll
    for (int off = 32; off > 0; off >>= 1) dot += __shfl_xor(dot, off, 64);
    if ((t & 63) == 0) red[t >> 6] = dot;
    __syncthreads();
    if (t == 0)
      dvec[b * 2048 + sp] = (red[0] + red[1] + red[2] + red[3]) * 0.03125f;
    __syncthreads();
  }
}

// ---------------------------------------------------------------- L3 Kc' + Vt
// Kc' = xc·M^T (npad x 1024): id = n*MTp + r (n in [0,8)). Vt = Wv xc^T + bv:
// id = baseV + m*MTp + r. T = 16*MTp <= 1024 even all-unmasked -> one round.
__global__ __launch_bounds__(256, 4) void kvt_gemm(
    const f16* __restrict__ xc, const f16* __restrict__ Wh,
    const f16* __restrict__ Mh, f16* __restrict__ Kc, f16* __restrict__ Vt,
    const float* __restrict__ bv, const int* __restrict__ npad) {
  __shared__ __align__(16) f16 As[128 * 64];
  __shared__ __align__(16) f16 Bs[128 * 64];
  int cum[5];
  cum[0] = 0;
#pragma unroll
  for (int b = 0; b < 4; ++b) cum[b + 1] = cum[b] + (npad[b] >> 7);
  const int rowsK = cum[4];
  const int MTp = (rowsK + 7) & ~7;
  const int baseV = 8 * MTp;
  const int T = 16 * MTp;

  for (int tile = blockIdx.x; tile < T; tile += gridDim.x) {
    if (tile < baseV) {
      const int n = tile / MTp, r = tile % MTp;
      if (r >= rowsK) continue;
      int b = 0;
      while (r >= cum[b + 1]) ++b;
      const int m = r - cum[b];
      gemm_body<f16>(As, Bs, xc + (long)b * 2097152, 1024, Mh, 1024,
                     Kc + (long)b * 2097152, 1024, nullptr, nullptr, 0, 0, 1.0f,
                     1024, m * 128, n * 128);
    } else {
      const int u = tile - baseV;
      const int m = u / MTp, r = u % MTp;
      if (r >= rowsK) continue;
      int b = 0;
      while (r >= cum[b + 1]) ++b;
      const int n = r - cum[b];
      gemm_body<f16>(As, Bs, Wh + 2097152, 1024, xc + (long)b * 2097152, 1024,
                     Vt + (long)b * 2097152, 2048, bv, bv, 0, 1, 1.0f, 1024,
                     m * 128, n * 128);
    }
  }
}

// ---------------------------------------------------------------- L4 S GEMM
// S = (xh·Kc'^T)/32 + dvec[col] (dvec pre-scaled). Kc'-panel-grouped.
__global__ __launch_bounds__(256, 4) void s_gemm128(
    const f16* __restrict__ xh, const f16* __restrict__ Kc, f16* __restrict__ Sbuf,
    const float* __restrict__ dvec, const int* __restrict__ npad) {
  __shared__ __align__(16) f16 As[128 * 64];
  __shared__ __align__(16) f16 Bs[128 * 64];
  int cum[5];
  cum[0] = 0;
#pragma unroll
  for (int b = 0; b < 4; ++b) cum[b + 1] = cum[b] + (npad[b] >> 7);
  const int rowsN = cum[4];
  const int Np = (rowsN + 7) & ~7;
  const int T = 16 * Np;

  for (int tile = blockIdx.x; tile < T; tile += gridDim.x) {
    const int m = tile / Np, rn = tile % Np;
    if (rn >= rowsN) continue;
    int b = 0;
    while (rn >= cum[b + 1]) ++b;
    const int n = rn - cum[b];
    gemm_body<f16>(As, Bs, xh + (long)b * 2097152, 1024,
                   Kc + (long)b * 2097152, 1024, Sbuf + (long)b * 4194304, 2048,
                   dvec + b * 2048, dvec + b * 2048, 1 << 30, 0, 0.03125f, 1024,
                   m * 128, n * 128);
  }
}

// ---------------------------------------------------------------- L5 softmax
__global__ LB256 void softmax_w(f16* __restrict__ S, const int* __restrict__ counts,
                                const int* __restrict__ npad) {
  const int wv = threadIdx.x >> 6, l = threadIdx.x & 63;
  const long r = (long)blockIdx.x * 4 + wv;
  const int b = (int)(r >> 11);
  const int nv = counts[b], np = npad[b];
  f16* row = S + r * 2048;

  float v[4][8];
  bool have[4];
  float mx = -3.0e38f;
#pragma unroll
  for (int g = 0; g < 4; ++g) {
    const int idx = (g * 64 + l) * 8;
    have[g] = idx < np;
    if (have[g]) {
      f16x8 sv = *(const f16x8*)(row + idx);
#pragma unroll
      for (int e = 0; e < 8; ++e) {
        float s = (idx + e < nv) ? (float)sv[e] : -3.0e38f;
        v[g][e] = s;
        mx = fmaxf(mx, s);
      }
    } else {
#pragma unroll
      for (int e = 0; e < 8; ++e) v[g][e] = -3.0e38f;
    }
  }
#pragma unroll
  for (int off = 32; off > 0; off >>= 1) mx = fmaxf(mx, __shfl_xor(mx, off, 64));

  float sum = 0.f;
  float ev[4][8];
#pragma unroll
  for (int g = 0; g < 4; ++g)
#pragma unroll
    for (int e = 0; e < 8; ++e) {
      float t = (v[g][e] <= -1.0e38f) ? 0.f : __expf(v[g][e] - mx);
      ev[g][e] = t;
      sum += t;
    }
#pragma unroll
  for (int off = 32; off > 0; off >>= 1) sum += __shfl_xor(sum, off, 64);
  const float inv = 1.f / sum;
#pragma unroll
  for (int g = 0; g < 4; ++g) {
    if (!have[g]) continue;
    const int idx = (g * 64 + l) * 8;
    f16x8 ov;
#pragma unroll
    for (int e = 0; e < 8; ++e) ov[e] = (f16)(ev[g][e] * inv);
    *(f16x8*)(row + idx) = ov;
  }
}

// ---------------------------------------------------------------- L6 PV GEMM
// O = P @ Vt^T (K=npad). rm = b*16+m; id = n*64 + rm -> Sbuf-panel XCD groups.
__global__ __launch_bounds__(256, 4) void pv_gemm128(
    const f16* __restrict__ Sbuf, const f16* __restrict__ Vt,
    float* __restrict__ out, const int* __restrict__ npad) {
  __shared__ __align__(16) f16 As[128 * 64];
  __shared__ __align__(16) f16 Bs[128 * 64];
  const int tile = blockIdx.x;
  const int n = tile >> 6, rm = tile & 63, b = rm >> 4, m = rm & 15;
  gemm_body<float>(As, Bs, Sbuf + (long)b * 4194304, 2048,
                   Vt + (long)b * 2097152, 2048, out + (long)b * 2097152,
                   1024, nullptr, nullptr, 0, 0, 1.0f, npad[b], m * 128,
                   n * 128);
}

// ---------------------------------------------------------------- launch
extern "C" void kernel_launch(void* const* d_in, const int* in_sizes, int n_in,
                              void* d_out, int out_size, void* d_ws, size_t ws_size,
                              hipStream_t stream) {
  const float* x = (const float*)d_in[0];
  const void* mask = d_in[1];
  const float* Wq = (const float*)d_in[2];
  const float* bq = (const float*)d_in[3];
  const float* Wk = (const float*)d_in[4];
  const float* bk = (const float*)d_in[5];
  const float* Wv = (const float*)d_in[6];
  const float* bv = (const float*)d_in[7];
  float* out = (float*)d_out;
  (void)bk;  // bk contributes a per-query constant to scores -> cancels

  // Workspace map (f16 units), ~108.1MB of the proven 118MB.
  f16* xh = (f16*)d_ws;            // 16MB
  f16* xc = xh + 8388608;          // 16MB
  f16* Wh = xc + 8388608;          // 6MB [Wq|Wk|Wv]
  f16* WqT = Wh + 3145728;         // 2MB
  f16* WkT = WqT + 1048576;        // 2MB
  f16* Mh = WkT + 1048576;         // 2MB
  f16* Kc = Mh + 1048576;          // 16MB
  f16* Vt = Kc + 8388608;          // 16MB
  f16* Sbuf = Vt + 8388608;        // 32MB
  float* wbuf = (float*)(Sbuf + 16777216);  // 4KB
  float* dvec = wbuf + 1024;       // 32KB
  int* sel = (int*)(dvec + 8192);
  int* counts = sel + 8192;
  int* npad = counts + 4;

  prep<<<1956, 256, 0, stream>>>(x, Wq, Wk, Wv, mask, bq, xh, Wh, WqT, WkT,
                                 wbuf, sel, counts, npad);
  gm<<<2112, 256, 0, stream>>>(xh, sel, counts, npad, xc, WqT, WkT, Mh, wbuf,
                               dvec);
  kvt_gemm<<<1024, 256, 0, stream>>>(xc, Wh, Mh, Kc, Vt, bv, npad);
  s_gemm128<<<1024, 256, 0, stream>>>(xh, Kc, Sbuf, dvec, npad);
  softmax_w<<<2048, 256, 0, stream>>>(Sbuf, counts, npad);
  pv_gemm128<<<512, 256, 0, stream>>>(Sbuf, Vt, out, npad);
}

// Round 11
// 224.714 us; speedup vs baseline: 1.1259x; 1.1259x over previous
//
#include <hip/hip_runtime.h>

// Fused attention with masked-key compaction, 6 dispatches, dense tile enumeration
// with XCD-aware grouping. R19 = R11 verbatim -- the session's best-measured
// kernel (221.5us). Ten rounds of experiments established:
//  - R9/R10: 8-phase deep pipelines REGRESS here (low occupancy exposes every
//    stall; K=1024 can't amortize prologues). Occupancy > pipeline depth.
//  - R12: sel-indirection in the K-loop spills (64 VGPR = zero headroom).
//  - R13: smaller tiles lose more to B-panel refetch than tail-packing gains.
//  - R14/R18: algebraic Q-GEMM elimination (M = Wq^T Wk) saves 25us of tiles
//    but costs ~+30us twice in dispatch overheads -> refuted empirically.
//  - R15/R16/R18: prep is ~53us at 1TB/s across THREE implementations ->
//    it absorbs the harness poison-fill drain; unoptimizable.
//  - R16: residency is hard-capped at 4 blocks/CU (1024 slots); grid size
//    beyond that does nothing.
//  - R17: GEMM dispatches cost ~57-63ns/tile LINEARLY; tile migration between
//    dispatches is neutral (total tiles conserved).
// Structure:
//  L1 prep:    cast x,W -> f16; per-batch mask scan (sel/counts/npad)
//  L2 gather:  xc[b][s'] = xh[b][sel[s']] (pad rows zeroed)
//  L3 qkvt:    {Q(512), K(8*MTp), Vt(8*MTp)} XCD-grouped, G=1024 @4/CU
//  L4 s128:    S = (Q Kc^T)/32, 128x128 body, Kc-panel-grouped, G=1024
//  L5 softmax: wave-per-row
//  L6 pv128:   O = P @ Vt^T (K=npad), 128x128 body, Sbuf-panel-grouped, G=512
// GEMM core: BK=64, global_load_lds w=16, XOR-swizzled LDS (0 conflicts),
// __launch_bounds__(256,4) (R8: 5 spills the accumulator).

typedef _Float16 f16;
typedef _Float16 f16x4 __attribute__((ext_vector_type(4)));
typedef _Float16 f16x8 __attribute__((ext_vector_type(8)));
typedef float f32x4 __attribute__((ext_vector_type(4)));

#define LB256 __launch_bounds__(256)

__device__ __forceinline__ void gld16(const void* gp, void* lp) {
  __builtin_amdgcn_global_load_lds(
      (__attribute__((address_space(1))) void*)(gp),
      (__attribute__((address_space(3))) void*)(lp),
      16, 0, 0);
}

// ---------------------------------------------------------------- 128x128 GEMM body
template <typename OutT>
__device__ __forceinline__ void gemm_body(
    f16* As, f16* Bs,
    const f16* __restrict__ A, int lda, const f16* __restrict__ B, int ldb,
    OutT* __restrict__ C, int ldc,
    const float* __restrict__ bias1, const float* __restrict__ bias2, int nb1,
    int bias_row, float scale, int K, int m0, int n0) {
  const int tid = threadIdx.x;
  const int w = tid >> 6, l = tid & 63;
  const int wm = (w >> 1) * 64, wn = (w & 1) * 64;
  const int quad = l >> 4, lo = l & 15;
  const int rl = l >> 3;
  const int scol = ((l & 7) ^ rl) * 8;
  const int swz = (quad ^ (lo & 3)) * 8;
  const int ks0 = ((lo >> 2) & 1) * 32;

  f32x4 acc[4][4] = {};
  for (int kk = 0; kk < K; kk += 64) {
#pragma unroll
    for (int r = 0; r < 4; ++r) {
      const int c8 = r * 4 + w;
      const int row = c8 * 8 + rl;
      gld16(A + (long)(m0 + row) * lda + kk + scol, &As[c8 * 512]);
      gld16(B + (long)(n0 + row) * ldb + kk + scol, &Bs[c8 * 512]);
    }
    __syncthreads();
#pragma unroll
    for (int ks = 0; ks < 2; ++ks) {
      const int kso = ks ? (32 - ks0) : ks0;
      f16x8 af[4], bf[4];
#pragma unroll
      for (int i = 0; i < 4; ++i)
        af[i] = *(const f16x8*)&As[(wm + i * 16 + lo) * 64 + swz + kso];
#pragma unroll
      for (int j = 0; j < 4; ++j)
        bf[j] = *(const f16x8*)&Bs[(wn + j * 16 + lo) * 64 + swz + kso];
#pragma unroll
      for (int i = 0; i < 4; ++i)
#pragma unroll
        for (int j = 0; j < 4; ++j)
          acc[i][j] = __builtin_amdgcn_mfma_f32_16x16x32_f16(af[i], bf[j],
                                                             acc[i][j], 0, 0, 0);
    }
    __syncthreads();
  }
#pragma unroll
  for (int i = 0; i < 4; ++i) {
    const int rowb = m0 + wm + i * 16 + quad * 4;
#pragma unroll
    for (int j = 0; j < 4; ++j) {
      const int col = n0 + wn + j * 16 + lo;
      float bc = 0.f;
      if (bias1 && !bias_row) bc = (col < nb1) ? bias1[col] : bias2[col - nb1];
#pragma unroll
      for (int r = 0; r < 4; ++r) {
        float bv = bias_row ? bias1[rowb + r] : bc;
        C[(long)(rowb + r) * ldc + col] = (OutT)(acc[i][j][r] * scale + bv);
      }
    }
  }
}

// ---------------------------------------------------------------- L1 prep
__global__ LB256 void prep(const float* __restrict__ x, const float* __restrict__ wq,
                           const float* __restrict__ wk, const float* __restrict__ wv,
                           const void* __restrict__ maskp, f16* __restrict__ xh,
                           f16* __restrict__ wh, int* __restrict__ sel,
                           int* __restrict__ counts, int* __restrict__ npad) {
  const int blk = blockIdx.x;
  const int t = threadIdx.x;
  if (blk < 11264) {
    long i = ((long)blk * 256 + t) * 4;
    const float* src;
    f16* dst;
    if (i < 8388608L) {
      src = x + i;
      dst = xh + i;
    } else {
      long j = i - 8388608L;
      int which = (int)(j >> 20);
      const float* ws = which == 0 ? wq : (which == 1 ? wk : wv);
      src = ws + (j & 1048575L);
      dst = wh + j;
    }
    float4 v = *(const float4*)src;
    f16x4 o;
    o[0] = (f16)v.x; o[1] = (f16)v.y; o[2] = (f16)v.z; o[3] = (f16)v.w;
    *(f16x4*)dst = o;
  } else {
    const int b = blk - 11264;
    __shared__ int bad;
    __shared__ int s[256];
    if (t == 0) bad = 0;
    __syncthreads();
    const int* mi = (const int*)maskp;
    int loc = 0;
    for (int i = t; i < 2048; i += 256)
      if ((unsigned)mi[i] > 1u) loc = 1;  // byte-packed bools look like big ints
    if (loc) atomicOr(&bad, 1);
    __syncthreads();
    const bool bytemode = bad != 0;
    int m[8];
    if (bytemode) {
      const unsigned char* p = (const unsigned char*)maskp + b * 2048 + t * 8;
#pragma unroll
      for (int e = 0; e < 8; ++e) m[e] = p[e] != 0;
    } else {
      const int* p = mi + b * 2048 + t * 8;
#pragma unroll
      for (int e = 0; e < 8; ++e) m[e] = p[e] != 0;
    }
    int local = 0;
#pragma unroll
    for (int e = 0; e < 8; ++e) local += m[e];
    s[t] = local;
    __syncthreads();
    for (int off = 1; off < 256; off <<= 1) {
      int v = (t >= off) ? s[t - off] : 0;
      __syncthreads();
      s[t] += v;
      __syncthreads();
    }
    int offp = s[t] - local;
#pragma unroll
    for (int e = 0; e < 8; ++e)
      if (m[e]) sel[b * 2048 + offp++] = t * 8 + e;
    if (t == 0) {
      counts[b] = s[255];
      npad[b] = ((s[255] + 127) >> 7) << 7;
    }
  }
}

// ---------------------------------------------------------------- L2 gather
__global__ LB256 void gather_x(const f16* __restrict__ xh, const int* __restrict__ sel,
                               const int* __restrict__ counts,
                               const int* __restrict__ npad, f16* __restrict__ xc) {
  const int b = blockIdx.y;
  const int np = npad[b], cnt = counts[b];
  const int t = threadIdx.x;
#pragma unroll
  for (int i = 0; i < 4; ++i) {
    const int sp = blockIdx.x * 4 + i;
    if (sp >= np) continue;
    f16* dst = xc + ((long)b * 2048 + sp) * 1024;
    if (sp >= cnt) {
      *(f16x4*)(dst + t * 4) = (f16x4){0, 0, 0, 0};
    } else {
      const f16* src = xh + ((long)b * 2048 + sel[b * 2048 + sp]) * 1024;
      *(f16x4*)(dst + t * 4) = *(const f16x4*)(src + t * 4);
    }
  }
}

// ---------------------------------------------------------------- L3 Q+K+Vt (XCD-grouped)
// Q tiles [0,512): id = n*64 + m -> the 8 n-tiles sharing A-rows m have ids = m
// (mod 8) -> same XCD L2. K/Vt: per-batch row-tiles flattened to r in [0,rowsK),
// padded to MTp (mult of 8); K id = 512 + n*MTp + r; Vt id = base2 + m*MTp + r.
__global__ __launch_bounds__(256, 4) void qkvt_gemm(
    const f16* __restrict__ xh, const f16* __restrict__ xc,
    const f16* __restrict__ Wh, f16* __restrict__ Qb, f16* __restrict__ Kc,
    f16* __restrict__ Vt, const float* __restrict__ bq,
    const float* __restrict__ bk, const float* __restrict__ bv,
    const int* __restrict__ npad) {
  __shared__ __align__(16) f16 As[128 * 64];
  __shared__ __align__(16) f16 Bs[128 * 64];
  int cum[5];
  cum[0] = 0;
#pragma unroll
  for (int b = 0; b < 4; ++b) cum[b + 1] = cum[b] + (npad[b] >> 7);
  const int rowsK = cum[4];
  const int MTp = (rowsK + 7) & ~7;
  const int base2 = 512 + 8 * MTp;
  const int T = base2 + 8 * MTp;

  for (int tile = blockIdx.x; tile < T; tile += gridDim.x) {
    if (tile < 512) {
      const int m = tile & 63, n = tile >> 6;
      gemm_body<f16>(As, Bs, xh, 1024, Wh, 1024, Qb, 1024, bq, bq, 1 << 30, 0,
                     1.0f, 1024, m * 128, n * 128);
    } else if (tile < base2) {
      const int u = tile - 512;
      const int n = u / MTp, r = u % MTp;
      if (r >= rowsK) continue;
      int b = 0;
      while (r >= cum[b + 1]) ++b;
      const int m = r - cum[b];
      gemm_body<f16>(As, Bs, xc + (long)b * 2048 * 1024, 1024, Wh + 1048576, 1024,
                     Kc + (long)b * 2048 * 1024, 1024, bk, bk, 1 << 30, 0, 1.0f,
                     1024, m * 128, n * 128);
    } else {
      const int u = tile - base2;
      const int m = u / MTp, r = u % MTp;
      if (r >= rowsK) continue;
      int b = 0;
      while (r >= cum[b + 1]) ++b;
      const int n = r - cum[b];
      gemm_body<f16>(As, Bs, Wh + 2097152, 1024, xc + (long)b * 2048 * 1024, 1024,
                     Vt + (long)b * 1024 * 2048, 2048, bv, bv, 0, 1, 1.0f, 1024,
                     m * 128, n * 128);
    }
  }
}

// ---------------------------------------------------------------- L4 S GEMM (128x128)
// Group by shared Kc panel (each Kc n-tile is read by 16 m-tiles): flatten (b,n)
// to rn in [0,rowsN), pad to Np (mult of 8); id = m*Np + rn -> same rn same XCD.
__global__ __launch_bounds__(256, 4) void s_gemm128(
    const f16* __restrict__ Qb, const f16* __restrict__ Kc, f16* __restrict__ Sbuf,
    const int* __restrict__ npad) {
  __shared__ __align__(16) f16 As[128 * 64];
  __shared__ __align__(16) f16 Bs[128 * 64];
  int cum[5];
  cum[0] = 0;
#pragma unroll
  for (int b = 0; b < 4; ++b) cum[b + 1] = cum[b] + (npad[b] >> 7);
  const int rowsN = cum[4];
  const int Np = (rowsN + 7) & ~7;
  const int T = 16 * Np;

  for (int tile = blockIdx.x; tile < T; tile += gridDim.x) {
    const int m = tile / Np, rn = tile % Np;
    if (rn >= rowsN) continue;
    int b = 0;
    while (rn >= cum[b + 1]) ++b;
    const int n = rn - cum[b];
    gemm_body<f16>(As, Bs, Qb + (long)b * 2048 * 1024, 1024,
                   Kc + (long)b * 2048 * 1024, 1024,
                   Sbuf + (long)b * 2048 * 2048, 2048, nullptr, nullptr, 0, 0,
                   0.03125f, 1024, m * 128, n * 128);
  }
}

// ---------------------------------------------------------------- L5 softmax (wave-per-row)
__global__ LB256 void softmax_w(f16* __restrict__ S, const int* __restrict__ counts,
                                const int* __restrict__ npad) {
  const int wv = threadIdx.x >> 6, l = threadIdx.x & 63;
  const long r = (long)blockIdx.x * 4 + wv;
  const int b = (int)(r >> 11);
  const int nv = counts[b], np = npad[b];
  f16* row = S + r * 2048;

  float v[4][8];
  bool have[4];
  float mx = -3.0e38f;
#pragma unroll
  for (int g = 0; g < 4; ++g) {
    const int idx = (g * 64 + l) * 8;
    have[g] = idx < np;
    if (have[g]) {
      f16x8 sv = *(const f16x8*)(row + idx);
#pragma unroll
      for (int e = 0; e < 8; ++e) {
        float s = (idx + e < nv) ? (float)sv[e] : -3.0e38f;
        v[g][e] = s;
        mx = fmaxf(mx, s);
      }
    } else {
#pragma unroll
      for (int e = 0; e < 8; ++e) v[g][e] = -3.0e38f;
    }
  }
#pragma unroll
  for (int off = 32; off > 0; off >>= 1) mx = fmaxf(mx, __shfl_xor(mx, off, 64));

  float sum = 0.f;
  float ev[4][8];
#pragma unroll
  for (int g = 0; g < 4; ++g)
#pragma unroll
    for (int e = 0; e < 8; ++e) {
      float t = (v[g][e] <= -1.0e38f) ? 0.f : __expf(v[g][e] - mx);
      ev[g][e] = t;
      sum += t;
    }
#pragma unroll
  for (int off = 32; off > 0; off >>= 1) sum += __shfl_xor(sum, off, 64);
  const float inv = 1.f / sum;
#pragma unroll
  for (int g = 0; g < 4; ++g) {
    if (!have[g]) continue;
    const int idx = (g * 64 + l) * 8;
    f16x8 ov;
#pragma unroll
    for (int e = 0; e < 8; ++e) ov[e] = (f16)(ev[g][e] * inv);
    *(f16x8*)(row + idx) = ov;
  }
}

// ---------------------------------------------------------------- L6 PV GEMM (128x128)
// O = P @ Vt^T (K=npad). rm = b*16+m in [0,64); id = n*64 + rm: the 8 n-tiles
// sharing Sbuf rows (b,m) have ids = rm (mod 8) -> same XCD. T = 512 exact.
__global__ __launch_bounds__(256, 4) void pv_gemm128(
    const f16* __restrict__ Sbuf, const f16* __restrict__ Vt,
    float* __restrict__ out, const int* __restrict__ npad) {
  __shared__ __align__(16) f16 As[128 * 64];
  __shared__ __align__(16) f16 Bs[128 * 64];
  const int tile = blockIdx.x;
  const int n = tile >> 6, rm = tile & 63, b = rm >> 4, m = rm & 15;
  gemm_body<float>(As, Bs, Sbuf + (long)b * 2048 * 2048, 2048,
                   Vt + (long)b * 1024 * 2048, 2048, out + (long)b * 2048 * 1024,
                   1024, nullptr, nullptr, 0, 0, 1.0f, npad[b], m * 128, n * 128);
}

// ---------------------------------------------------------------- launch
extern "C" void kernel_launch(void* const* d_in, const int* in_sizes, int n_in,
                              void* d_out, int out_size, void* d_ws, size_t ws_size,
                              hipStream_t stream) {
  const float* x = (const float*)d_in[0];
  const void* mask = d_in[1];
  const float* Wq = (const float*)d_in[2];
  const float* bq = (const float*)d_in[3];
  const float* Wk = (const float*)d_in[4];
  const float* bk = (const float*)d_in[5];
  const float* Wv = (const float*)d_in[6];
  const float* bv = (const float*)d_in[7];
  float* out = (float*)d_out;

  // Workspace (f16 elems), 118 MB total (proven available in R1).
  f16* xh = (f16*)d_ws;              // 8M  [0,16MB)
  f16* xc = xh + 8388608;            // 8M  [16,32)
  f16* Wh = xc + 8388608;            // 3M  [32,38)  [Wq|Wk|Wv]
  f16* Qb = Wh + 3145728;            // 8M  [38,54)
  f16* Kc = Qb + 8388608;            // 8M  [54,70)
  f16* Vt = Kc + 8388608;            // 8M  [70,86)
  f16* Sbuf = Vt + 8388608;          // 16M [86,118)
  int* sel = (int*)(Sbuf + 16777216);
  int* counts = sel + 8192;
  int* npad = counts + 4;

  prep<<<11268, 256, 0, stream>>>(x, Wq, Wk, Wv, mask, xh, Wh, sel, counts, npad);
  gather_x<<<dim3(512, 4), 256, 0, stream>>>(xh, sel, counts, npad, xc);
  qkvt_gemm<<<1024, 256, 0, stream>>>(xh, xc, Wh, Qb, Kc, Vt, bq, bk, bv, npad);
  s_gemm128<<<1024, 256, 0, stream>>>(Qb, Kc, Sbuf, npad);
  softmax_w<<<2048, 256, 0, stream>>>(Sbuf, counts, npad);
  pv_gemm128<<<512, 256, 0, stream>>>(Sbuf, Vt, out, npad);
}